// Round 13
// baseline (897.496 us; speedup 1.0000x reference)
//
#include <hip/hip_runtime.h>

#define NB 8
#define NP 16384
#define NC 256
#define NH 128
#define NM 4096
#define NS 1024

typedef float v2f __attribute__((ext_vector_type(2)));

// ---------- helpers ----------
__device__ __forceinline__ unsigned long long make_key(float v, int n) {
  unsigned u = __float_as_uint(v);
  u = (u & 0x80000000u) ? ~u : (u | 0x80000000u);  // map float -> ascending uint
  unsigned d = ~u;                                 // descending
  return (((unsigned long long)d) << 32) | (unsigned)n;
}

__device__ __forceinline__ void ce64(unsigned long long& a, unsigned long long& c, bool up) {
  unsigned long long x = a, y = c;
  if ((x > y) == up) { a = y; c = x; }
}

// VALU-only 64-lane max (values >= 0), result broadcast via readlane(63).
__device__ __forceinline__ float wave_max_dpp(float v) {
#define DPPMAX(ctrl)                                                            \
  v = fmaxf(v, __int_as_float(__builtin_amdgcn_update_dpp(                      \
                 __float_as_int(v), __float_as_int(v), (ctrl), 0xf, 0xf, false)))
  DPPMAX(0xB1);   // quad_perm [1,0,3,2]  : xor 1
  DPPMAX(0x4E);   // quad_perm [2,3,0,1]  : xor 2
  DPPMAX(0x141);  // row_half_mirror
  DPPMAX(0x140);  // row_mirror
  DPPMAX(0x142);  // row_bcast15
  DPPMAX(0x143);  // row_bcast31
#undef DPPMAX
  return __int_as_float(__builtin_amdgcn_readlane(__float_as_int(v), 63));
}

// ---------- seg branch: 128x128 tile, 8x8 acc/thread, b128 LDS reads ----------
// Weights staged directly from row-major w1 [o][c]; values entering wt[kk][o]
// are bit-identical to the old transpose+load path.
__global__ __launch_bounds__(256) void seg_kernel(
    const float* __restrict__ w1, const float* __restrict__ features,
    const float* __restrict__ scale1, const float* __restrict__ bias1,
    const float* __restrict__ w2, const float* __restrict__ b2,
    float* __restrict__ seg_out, unsigned long long* __restrict__ keys) {
  __shared__ float wt[32][128];   // 16 KB
  __shared__ float ft[32][128];   // 16 KB
  __shared__ float red[16][128];  // 8 KB
  __shared__ float Ssh[128];
  __shared__ float w2sh[128];
  int b = blockIdx.y;
  int n0 = blockIdx.x * 128;
  int tid = threadIdx.x;
  int lane = tid & 63;
  int ro = tid >> 4, rc = tid & 15;
  float a0 = w2[lane], a1 = w2[lane + 64];
  float whi = fmaxf(a0, a1), wlo = fminf(a0, a1);
#pragma unroll
  for (int off = 32; off >= 1; off >>= 1) {
    whi = fmaxf(whi, __shfl_xor(whi, off, 64));
    wlo = fminf(wlo, __shfl_xor(wlo, off, 64));
  }
  if (tid < 128) w2sh[tid] = w2[tid];
  const float* fb = features + (size_t)b * NC * NP;
  float acc[8][8] = {};
  for (int kc = 0; kc < NC; kc += 32) {
    // stage wt[kk][o] from w1[o][kc+kk]: float4 along c, scatter LDS stores
#pragma unroll
    for (int t = 0; t < 4; ++t) {
      int q = tid + t * 256;          // 0..1023
      int o = q >> 3, c4 = (q & 7) * 4;
      float4 v = *(const float4*)&w1[o * NC + kc + c4];
      wt[c4 + 0][o] = v.x;
      wt[c4 + 1][o] = v.y;
      wt[c4 + 2][o] = v.z;
      wt[c4 + 3][o] = v.w;
    }
#pragma unroll
    for (int t = 0; t < 4; ++t) {
      int q = tid + t * 256;
      int kk = q >> 5, c4 = (q & 31) * 4;
      *(float4*)&ft[kk][c4] = *(const float4*)&fb[(size_t)(kc + kk) * NP + n0 + c4];
    }
    __syncthreads();
#pragma unroll
    for (int kk = 0; kk < 32; ++kk) {
      float wv[8], fv[8];
#pragma unroll
      for (int i = 0; i < 8; ++i) wv[i] = wt[kk][ro * 8 + i];
#pragma unroll
      for (int j = 0; j < 8; ++j) fv[j] = ft[kk][rc * 8 + j];
#pragma unroll
      for (int i = 0; i < 8; ++i)
#pragma unroll
        for (int j = 0; j < 8; ++j) acc[i][j] = fmaf(wv[i], fv[j], acc[i][j]);
    }
    __syncthreads();
  }
  float part[8] = {};
#pragma unroll
  for (int i = 0; i < 8; ++i) {
    int o = ro * 8 + i;
    float sc = scale1[o], bi = bias1[o];
#pragma unroll
    for (int j = 0; j < 8; ++j) {
      float h = fmaxf(fmaf(acc[i][j], sc, bi), 0.0f);
      part[j] += h;
    }
  }
#pragma unroll
  for (int j = 0; j < 8; ++j) red[ro][rc * 8 + j] = part[j];
  __syncthreads();
  float b2v = b2[0];
  if (tid < 128) {
    float S = 0.0f;
#pragma unroll
    for (int r = 0; r < 16; ++r) S += red[r][tid];  // o-ascending, same tree
    Ssh[tid] = S;
    float m = (S >= 0.0f ? whi * S : wlo * S) + b2v;
    float sig = 1.0f / (1.0f + expf(-m));
    int nn = n0 + tid;
    keys[(size_t)b * NP + nn] = make_key(sig, nn);
  }
  __syncthreads();
#pragma unroll
  for (int t = 0; t < 16; ++t) {
    int q = tid + t * 256;            // 0..4095
    int k = q >> 5, n4 = (q & 31) * 4;
    float w2k = w2sh[k];
    const float4 s4 = *(const float4*)&Ssh[n4];
    float4 sv;
    sv.x = fmaf(w2k, s4.x, b2v);
    sv.y = fmaf(w2k, s4.y, b2v);
    sv.z = fmaf(w2k, s4.z, b2v);
    sv.w = fmaf(w2k, s4.w, b2v);
    *(float4*)&seg_out[((size_t)b * 128 + k) * NP + n0 + n4] = sv;
  }
}

// ---------- bitonic sort of each 8192-key chunk, register-fused steps ----------
__global__ __launch_bounds__(1024) void sort8k_kernel(unsigned long long* __restrict__ keys) {
  __shared__ unsigned long long sk[8192];
  int chunk = blockIdx.x & 1, b = blockIdx.x >> 1;
  bool desc = (chunk == 1);
  unsigned long long* K = keys + (size_t)b * NP + chunk * 8192;
  int tid = threadIdx.x;
  for (int i = tid; i < 8192; i += 1024) sk[i] = K[i];
  __syncthreads();
  for (int k = 2; k <= 8192; k <<= 1) {
    int j = k >> 1;
    while (j >= 8) {
      if (j >= 32) {
        int ja = j, jb = j >> 1, jc = j >> 2;
        int x = tid;
        x = (x & (jc - 1)) | ((x & ~(jc - 1)) << 1);
        x = (x & (jb - 1)) | ((x & ~(jb - 1)) << 1);
        x = (x & (ja - 1)) | ((x & ~(ja - 1)) << 1);
        unsigned long long e[8];
        e[0] = sk[x];           e[1] = sk[x | jc];
        e[2] = sk[x | jb];      e[3] = sk[x | jb | jc];
        e[4] = sk[x | ja];      e[5] = sk[x | ja | jc];
        e[6] = sk[x | ja | jb]; e[7] = sk[x | ja | jb | jc];
        bool up = ((x & k) == 0) != desc;
        ce64(e[0], e[4], up); ce64(e[1], e[5], up); ce64(e[2], e[6], up); ce64(e[3], e[7], up);
        ce64(e[0], e[2], up); ce64(e[1], e[3], up); ce64(e[4], e[6], up); ce64(e[5], e[7], up);
        ce64(e[0], e[1], up); ce64(e[2], e[3], up); ce64(e[4], e[5], up); ce64(e[6], e[7], up);
        sk[x] = e[0];           sk[x | jc] = e[1];
        sk[x | jb] = e[2];      sk[x | jb | jc] = e[3];
        sk[x | ja] = e[4];      sk[x | ja | jc] = e[5];
        sk[x | ja | jb] = e[6]; sk[x | ja | jb | jc] = e[7];
        j >>= 3;
      } else if (j >= 16) {
        int ja = j, jb = j >> 1;
        for (int g = tid; g < 2048; g += 1024) {
          int x = g;
          x = (x & (jb - 1)) | ((x & ~(jb - 1)) << 1);
          x = (x & (ja - 1)) | ((x & ~(ja - 1)) << 1);
          unsigned long long e0 = sk[x], e1 = sk[x | jb];
          unsigned long long e2 = sk[x | ja], e3 = sk[x | ja | jb];
          bool up = ((x & k) == 0) != desc;
          ce64(e0, e2, up); ce64(e1, e3, up);
          ce64(e0, e1, up); ce64(e2, e3, up);
          sk[x] = e0; sk[x | jb] = e1; sk[x | ja] = e2; sk[x | ja | jb] = e3;
        }
        j >>= 2;
      } else {  // j == 8
        for (int g = tid; g < 4096; g += 1024) {
          int i = (g & 7) | ((g & ~7) << 1);
          bool up = ((i & k) == 0) != desc;
          unsigned long long a = sk[i], c = sk[i | 8];
          if ((a > c) == up) { sk[i] = c; sk[i | 8] = a; }
        }
        j >>= 1;
      }
      __syncthreads();
    }
    {  // tail: j in {4,2,1} (j < k), inside own 8 contiguous elements
      int base = tid * 8;
      unsigned long long e[8];
#pragma unroll
      for (int t = 0; t < 8; ++t) e[t] = sk[base + t];
#pragma unroll
      for (int jj = 4; jj >= 1; jj >>= 1) {
        if (jj > (k >> 1)) continue;
#pragma unroll
        for (int t = 0; t < 8; ++t)
          if (!(t & jj)) {
            bool up = (((base + t) & k) == 0) != desc;
            ce64(e[t], e[t | jj], up);
          }
      }
#pragma unroll
      for (int t = 0; t < 8; ++t) sk[base + t] = e[t];
    }
    __syncthreads();
  }
  for (int i = tid; i < 8192; i += 1024) K[i] = sk[i];
}

// ---------- bitonic merge of lower half (ascending), fused steps ----------
__global__ __launch_bounds__(1024) void merge_topk_kernel(
    const unsigned long long* __restrict__ keys, int* __restrict__ fg_idx,
    float* __restrict__ fg_xyz, const float* __restrict__ xyz) {
  __shared__ unsigned long long sk[8192];
  int b = blockIdx.x;
  const unsigned long long* K = keys + (size_t)b * NP;
  int tid = threadIdx.x;
  for (int i = tid; i < 8192; i += 1024) {
    unsigned long long a = K[i], c = K[i + 8192];
    sk[i] = (a < c) ? a : c;
  }
  __syncthreads();
  int j = 4096;
  while (j >= 8) {
    if (j >= 32) {
      int ja = j, jb = j >> 1, jc = j >> 2;
      int x = tid;
      x = (x & (jc - 1)) | ((x & ~(jc - 1)) << 1);
      x = (x & (jb - 1)) | ((x & ~(jb - 1)) << 1);
      x = (x & (ja - 1)) | ((x & ~(ja - 1)) << 1);
      unsigned long long e[8];
      e[0] = sk[x];           e[1] = sk[x | jc];
      e[2] = sk[x | jb];      e[3] = sk[x | jb | jc];
      e[4] = sk[x | ja];      e[5] = sk[x | ja | jc];
      e[6] = sk[x | ja | jb]; e[7] = sk[x | ja | jb | jc];
      ce64(e[0], e[4], true); ce64(e[1], e[5], true); ce64(e[2], e[6], true); ce64(e[3], e[7], true);
      ce64(e[0], e[2], true); ce64(e[1], e[3], true); ce64(e[4], e[6], true); ce64(e[5], e[7], true);
      ce64(e[0], e[1], true); ce64(e[2], e[3], true); ce64(e[4], e[5], true); ce64(e[6], e[7], true);
      sk[x] = e[0];           sk[x | jc] = e[1];
      sk[x | jb] = e[2];      sk[x | jb | jc] = e[3];
      sk[x | ja] = e[4];      sk[x | ja | jc] = e[5];
      sk[x | ja | jb] = e[6]; sk[x | ja | jb | jc] = e[7];
      j >>= 3;
    } else if (j >= 16) {
      int ja = j, jb = j >> 1;
      for (int g = tid; g < 2048; g += 1024) {
        int x = g;
        x = (x & (jb - 1)) | ((x & ~(jb - 1)) << 1);
        x = (x & (ja - 1)) | ((x & ~(ja - 1)) << 1);
        unsigned long long e0 = sk[x], e1 = sk[x | jb];
        unsigned long long e2 = sk[x | ja], e3 = sk[x | ja | jb];
        ce64(e0, e2, true); ce64(e1, e3, true);
        ce64(e0, e1, true); ce64(e2, e3, true);
        sk[x] = e0; sk[x | jb] = e1; sk[x | ja] = e2; sk[x | ja | jb] = e3;
      }
      j >>= 2;
    } else {  // j == 8
      for (int g = tid; g < 4096; g += 1024) {
        int i = (g & 7) | ((g & ~7) << 1);
        unsigned long long a = sk[i], c = sk[i | 8];
        if (a > c) { sk[i] = c; sk[i | 8] = a; }
      }
      j >>= 1;
    }
    __syncthreads();
  }
  {  // tail j=4,2,1 ascending, own 8 contiguous
    int base = tid * 8;
    unsigned long long e[8];
#pragma unroll
    for (int t = 0; t < 8; ++t) e[t] = sk[base + t];
    ce64(e[0], e[4], true); ce64(e[1], e[5], true); ce64(e[2], e[6], true); ce64(e[3], e[7], true);
    ce64(e[0], e[2], true); ce64(e[1], e[3], true); ce64(e[4], e[6], true); ce64(e[5], e[7], true);
    ce64(e[0], e[1], true); ce64(e[2], e[3], true); ce64(e[4], e[5], true); ce64(e[6], e[7], true);
#pragma unroll
    for (int t = 0; t < 8; ++t) sk[base + t] = e[t];
  }
  __syncthreads();
  for (int m = tid; m < NM; m += 1024) {
    unsigned long long key = sk[m];
    int idx = (int)(key & 0xffffffffULL);
    fg_idx[b * NM + m] = idx;
    size_t src = ((size_t)b * NP + idx) * 3;
    size_t dst = ((size_t)b * NM + m) * 3;
    fg_xyz[dst + 0] = xyz[src + 0];
    fg_xyz[dst + 1] = xyz[src + 1];
    fg_xyz[dst + 2] = xyz[src + 2];
  }
}

// ---------- vote branch: gathered GEMM -> vh, reg head, clip, ctr points ----------
__global__ __launch_bounds__(256) void vote_kernel(
    const float* __restrict__ features, const int* __restrict__ fg_idx,
    const float* __restrict__ w1, const float* __restrict__ scale1,
    const float* __restrict__ bias1, const float* __restrict__ rw,
    const float* __restrict__ rb, const float* __restrict__ fg_xyz,
    float* __restrict__ vh, float* __restrict__ offs, float* __restrict__ fg_ctr) {
  __shared__ float wt[32][128];
  __shared__ float ft[32][64];
  __shared__ float hl[128][65];
  __shared__ int idx_l[64];
  int b = blockIdx.y;
  int m0 = blockIdx.x * 64;
  int tid = threadIdx.x;
  int ro = tid >> 4, rc = tid & 15;
  const float* fb = features + (size_t)b * NC * NP;
  if (tid < 64) idx_l[tid] = fg_idx[b * NM + m0 + tid];
  __syncthreads();
  float acc[8][4] = {};
  for (int kc = 0; kc < NC; kc += 32) {
#pragma unroll
    for (int t = 0; t < 4; ++t) {
      int q = tid + t * 256;          // 0..1023
      int o = q >> 3, c4 = (q & 7) * 4;
      float4 v = *(const float4*)&w1[o * NC + kc + c4];
      wt[c4 + 0][o] = v.x;
      wt[c4 + 1][o] = v.y;
      wt[c4 + 2][o] = v.z;
      wt[c4 + 3][o] = v.w;
    }
    for (int q = tid; q < 2048; q += 256) {
      int kk = q >> 6, mm = q & 63;
      ft[kk][mm] = fb[(size_t)(kc + kk) * NP + idx_l[mm]];
    }
    __syncthreads();
#pragma unroll
    for (int kk = 0; kk < 32; ++kk) {
      float wv[8], fv[4];
#pragma unroll
      for (int i = 0; i < 8; ++i) wv[i] = wt[kk][ro * 8 + i];
#pragma unroll
      for (int j = 0; j < 4; ++j) fv[j] = ft[kk][rc * 4 + j];
#pragma unroll
      for (int i = 0; i < 8; ++i)
#pragma unroll
        for (int j = 0; j < 4; ++j) acc[i][j] = fmaf(wv[i], fv[j], acc[i][j]);
    }
    __syncthreads();
  }
#pragma unroll
  for (int i = 0; i < 8; ++i) {
    int o = ro * 8 + i;
    float sc = scale1[o], bi = bias1[o];
#pragma unroll
    for (int j = 0; j < 4; ++j) {
      float h = fmaxf(fmaf(acc[i][j], sc, bi), 0.0f);
      hl[o][rc * 4 + j] = h;
      vh[((size_t)b * NH + o) * NM + m0 + rc * 4 + j] = h;
    }
  }
  __syncthreads();
  if (tid < 64) {
    int m = m0 + tid;
    const float MT[3] = {3.0f, 3.0f, 2.0f};
#pragma unroll
    for (int r = 0; r < 3; ++r) {
      float a = 0.0f;
      for (int o = 0; o < NH; ++o) a = fmaf(rw[r * NH + o], hl[o][tid], a);
      a += rb[r];
      a = fminf(fmaxf(a, -MT[r]), MT[r]);
      size_t p = ((size_t)b * NM + m) * 3 + r;
      offs[p] = a;
      fg_ctr[p] = __fadd_rn(fg_xyz[p], a);
    }
  }
}

// ---------- D-FPS: frozen R9 structure, 4 waves x 16 pts/lane ----------
#define PPT 16
__global__ __launch_bounds__(256) void fps_kernel(
    const float* __restrict__ fg_xyz, const float* __restrict__ fg_ctr,
    int* __restrict__ ori_idx, int* __restrict__ ctr_idx) {
#pragma clang fp contract(off)
  __shared__ float px[NM], py[NM], pz[NM];          // 48 KB
  __shared__ __align__(32) unsigned long long wkey[2][4];
  __shared__ int sel_list[NS];
  int set = blockIdx.x & 1, b = blockIdx.x >> 1;
  const float* P = (set == 0 ? fg_xyz : fg_ctr) + (size_t)b * NM * 3;
  int* O = (set == 0 ? ori_idx : ctr_idx) + b * NS;
  int tid = threadIdx.x;
  for (int m = tid; m < NM; m += 256) {
    px[m] = P[m * 3 + 0];
    py[m] = P[m * 3 + 1];
    pz[m] = P[m * 3 + 2];
  }
  __syncthreads();
  v2f x2[8], y2[8], z2[8], d2[8];
  int base_idx = tid * PPT;
#pragma unroll
  for (int j = 0; j < 8; ++j) {
    int m0 = base_idx + 2 * j, m1 = m0 + 1;
    v2f t;
    t.x = px[m0]; t.y = px[m1]; x2[j] = t;
    t.x = py[m0]; t.y = py[m1]; y2[j] = t;
    t.x = pz[m0]; t.y = pz[m1]; z2[j] = t;
    t.x = 3.402823466e38f; t.y = 3.402823466e38f;  // fmin(FLT_MAX,d0)==d0
    d2[j] = t;
  }
  if (tid == 0) sel_list[0] = 0;
  int lane = tid & 63, wave = tid >> 6;  // 4 waves
  float sx = px[0], sy = py[0], sz = pz[0];
  for (int it = 1; it < NS; ++it) {
    v2f sxv, syv, szv;
    sxv.x = sx; sxv.y = sx;
    syv.x = sy; syv.y = sy;
    szv.x = sz; szv.y = sz;
    float bd = -1.0f;
    int bc = base_idx;
#pragma unroll
    for (int j = 0; j < 8; ++j) {
      v2f dx = x2[j] - sxv, dy = y2[j] - syv, dz = z2[j] - szv;
      v2f dd = (dx * dx + dy * dy) + dz * dz;  // rn, np association
      v2f nd;
      nd.x = fminf(d2[j].x, dd.x);
      nd.y = fminf(d2[j].y, dd.y);
      d2[j] = nd;
      if (j == 0) {
        bd = nd.x; bc = base_idx;
        bool g = nd.y > bd; bd = g ? nd.y : bd; bc = g ? base_idx + 1 : bc;
      } else {
        bool g0 = nd.x > bd; bd = g0 ? nd.x : bd; bc = g0 ? base_idx + 2 * j : bc;
        bool g1 = nd.y > bd; bd = g1 ? nd.y : bd; bc = g1 ? base_idx + 2 * j + 1 : bc;
      }
    }
    float wm = wave_max_dpp(bd);
    unsigned long long msk = __ballot(bd == wm);
    int wl = __ffsll((long long)msk) - 1;
    if (lane == wl)
      wkey[it & 1][wave] =
          (((unsigned long long)__float_as_uint(bd)) << 32) | (unsigned)(4095 - bc);
    __syncthreads();
    const ulonglong2* wk = (const ulonglong2*)&wkey[it & 1][0];
    ulonglong2 q0 = wk[0], q1 = wk[1];
    unsigned long long m0 = q0.x > q0.y ? q0.x : q0.y;
    unsigned long long m1 = q1.x > q1.y ? q1.x : q1.y;
    unsigned long long km = m0 > m1 ? m0 : m1;
    int sel = 4095 - (int)(km & 0xffffffffULL);
    if (tid == 0) sel_list[it] = sel;  // LDS, not global (vmcnt-free barrier)
    sx = px[sel]; sy = py[sel]; sz = pz[sel];  // broadcast reads
  }
  __syncthreads();
  for (int s2 = tid; s2 < NS; s2 += 256) O[s2] = sel_list[s2];
}

// ---------- fused outputs: agg_feat (y<32) + xyz/offset/origin (y==32) ----------
__global__ __launch_bounds__(256) void out_kernel(
    const float* __restrict__ vh, const float* __restrict__ features,
    const int* __restrict__ fg_idx, const int* __restrict__ ori_idx,
    const int* __restrict__ ctr_idx, const float* __restrict__ fg_xyz,
    const float* __restrict__ fg_ctr, const float* __restrict__ offs,
    float* __restrict__ out_feat, float* __restrict__ out_agg,
    float* __restrict__ out_cxyz, float* __restrict__ out_coff,
    float* __restrict__ out_corg) {
  int b = blockIdx.z;
  if (blockIdx.y < 32) {
    int o = blockIdx.y * 4 + (threadIdx.x >> 6);
    int s = blockIdx.x * 64 + (threadIdx.x & 63);
    float val;
    if (s < NS) {
      int i = ctr_idx[b * NS + s];
      val = vh[((size_t)b * NH + o) * NM + i];
    } else {
      int i = ori_idx[b * NS + (s - NS)];
      int g = fg_idx[b * NM + i];
      val = features[((size_t)b * NC + o) * NP + g];
    }
    out_feat[((size_t)b * NH + o) * (2 * NS) + s] = val;
  } else if (blockIdx.x < 8) {
    int s = blockIdx.x * 256 + threadIdx.x;  // 0..2047
    if (s < NS) {
      int i = ctr_idx[b * NS + s];
      size_t src = ((size_t)b * NM + i) * 3;
      size_t d_agg = ((size_t)b * 2 * NS + s) * 3;
      size_t d_s = ((size_t)b * NS + s) * 3;
#pragma unroll
      for (int r = 0; r < 3; ++r) {
        float c = fg_ctr[src + r];
        out_agg[d_agg + r] = c;
        out_cxyz[d_s + r] = c;
        out_coff[d_s + r] = offs[src + r];
        out_corg[d_s + r] = fg_xyz[src + r];
      }
    } else {
      int i = ori_idx[b * NS + (s - NS)];
      size_t src = ((size_t)b * NM + i) * 3;
      size_t d_agg = ((size_t)b * 2 * NS + s) * 3;
#pragma unroll
      for (int r = 0; r < 3; ++r) out_agg[d_agg + r] = fg_xyz[src + r];
    }
  }
}

extern "C" void kernel_launch(void* const* d_in, const int* in_sizes, int n_in,
                              void* d_out, int out_size, void* d_ws, size_t ws_size,
                              hipStream_t stream) {
  const float* xyz = (const float*)d_in[0];
  const float* features = (const float*)d_in[1];
  const float* seg_w1 = (const float*)d_in[2];
  const float* seg_scale1 = (const float*)d_in[3];
  const float* seg_bias1 = (const float*)d_in[4];
  const float* seg_w2 = (const float*)d_in[5];
  const float* seg_b2 = (const float*)d_in[6];
  const float* vote_w1 = (const float*)d_in[7];
  const float* vote_scale1 = (const float*)d_in[8];
  const float* vote_bias1 = (const float*)d_in[9];
  const float* reg_w = (const float*)d_in[10];
  const float* reg_b = (const float*)d_in[11];
  float* out = (float*)d_out;

  char* ws = (char*)d_ws;
  unsigned long long* keys = (unsigned long long*)(ws + 0);  // 1,048,576 B
  int* fg_idx = (int*)(ws + 1048576);                        // 131,072 B
  float* fg_xyz = (float*)(ws + 1179648);                    // 393,216 B
  float* fg_ctr = (float*)(ws + 1572864);                    // 393,216 B
  float* offs = (float*)(ws + 1966080);                      // 393,216 B
  int* ori_idx = (int*)(ws + 2359296);                       // 32,768 B
  int* ctr_idx = (int*)(ws + 2392064);                       // 32,768 B
  float* vh = (float*)(ws + 2424832);                        // 16,777,216 B

  // outputs (reference return order), seg is [B,128,N]:
  float* out_agg_xyz = out;                  // [8,2048,3]      @ 0
  float* out_agg_feat = out + 49152;         // [8,128,2048]    @ 49152
  float* out_ctr_xyz = out + 2146304;        // [8,1024,3]      @ 2146304
  float* out_ctr_off = out + 2170880;        // [8,1024,3]      @ 2170880
  float* out_ctr_org = out + 2195456;        // [8,1024,3]      @ 2195456
  float* out_seg = out + 2220032;            // [8,128,16384]   @ 2220032

  seg_kernel<<<dim3(NP / 128, NB), 256, 0, stream>>>(
      seg_w1, features, seg_scale1, seg_bias1, seg_w2, seg_b2, out_seg, keys);
  sort8k_kernel<<<2 * NB, 1024, 0, stream>>>(keys);
  merge_topk_kernel<<<NB, 1024, 0, stream>>>(keys, fg_idx, fg_xyz, xyz);
  vote_kernel<<<dim3(NM / 64, NB), 256, 0, stream>>>(
      features, fg_idx, vote_w1, vote_scale1, vote_bias1, reg_w, reg_b, fg_xyz,
      vh, offs, fg_ctr);
  fps_kernel<<<16, 256, 0, stream>>>(fg_xyz, fg_ctr, ori_idx, ctr_idx);
  out_kernel<<<dim3(32, 33, NB), 256, 0, stream>>>(
      vh, features, fg_idx, ori_idx, ctr_idx, fg_xyz, fg_ctr, offs,
      out_agg_feat, out_agg_xyz, out_ctr_xyz, out_ctr_off, out_ctr_org);
}